// Round 1
// baseline (229.528 us; speedup 1.0000x reference)
//
#include <hip/hip_runtime.h>
#include <math.h>

#define A_ 5
#define C_ 20
#define N_ 64
#define H_ 52
#define W_ 52
#define HW_ (H_ * W_)     // 2704
#define M_ 32
#define CH_ (A_ * (5 + C_)) // 125

__device__ __forceinline__ float sigmoidf_(float v) {
    return 1.0f / (1.0f + expf(-v));
}

__global__ __launch_bounds__(256) void yolo_loss_kernel(
    const float* __restrict__ x,       // (N, 125, H, W)
    const float* __restrict__ anchors, // (5, 2)
    const float* __restrict__ gt,      // (N, 32, 4)
    const int* __restrict__ glab,      // (N, 32)
    const void* img_h_p, const void* img_w_p,
    float* __restrict__ out)           // 3 floats
{
    __shared__ float s_g[M_][4];
    __shared__ float s_area[M_];
    __shared__ int   s_lab[M_];
    __shared__ float s_anch[A_ * 2];

    const int n = blockIdx.y;
    const int tid = threadIdx.x;
    const int cell = blockIdx.x * 256 + tid;

    // ---- stage GT boxes / areas / labels / anchors into LDS ----
    if (tid < M_) {
        float g0 = gt[((size_t)n * M_ + tid) * 4 + 0];
        float g1 = gt[((size_t)n * M_ + tid) * 4 + 1];
        float g2 = gt[((size_t)n * M_ + tid) * 4 + 2];
        float g3 = gt[((size_t)n * M_ + tid) * 4 + 3];
        s_g[tid][0] = g0; s_g[tid][1] = g1;
        s_g[tid][2] = g2; s_g[tid][3] = g3;
        s_area[tid] = (g2 - g0) * (g3 - g1);
        s_lab[tid] = glab[n * M_ + tid];
    } else if (tid >= 64 && tid < 64 + A_ * 2) {
        s_anch[tid - 64] = anchors[tid - 64];
    }
    __syncthreads();

    // ---- decode img scale (int per spec; float-bit-pattern fallback) ----
    int ibw = *(const int*)img_w_p;
    float img_w = (ibw > 0 && ibw < 1000000) ? (float)ibw : *(const float*)img_w_p;
    int ibh = *(const int*)img_h_p;
    float img_h = (ibh > 0 && ibh < 1000000) ? (float)ibh : *(const float*)img_h_p;
    const float sx = img_w / (float)W_;   // 32
    const float sy = img_h / (float)H_;   // 32

    float obj_s = 0.0f, bbox_s = 0.0f, clf_s = 0.0f;

    if (cell < HW_) {
        const int wi = cell % W_;
        const int hi = cell / W_;
        const float cx = (float)wi * sx;
        const float cy = (float)hi * sy;

        // running best over anchors (cross-mult iou comparison, first-max ties)
        float best_i = 0.0f, best_u = 1.0f;
        int   best_a = 0, best_m = 0;
        float sxl = 0.f, syl = 0.f, sxr = 0.f, syr = 0.f, so = 0.f;
        float bomax = -1e30f;

        const size_t nbase = (size_t)n * CH_ * HW_ + (size_t)cell;

        #pragma unroll
        for (int a = 0; a < A_; ++a) {
            const float* p = x + nbase + (size_t)a * 25 * HW_;
            float t0 = p[0];
            float t1 = p[HW_];
            float t2 = p[2 * (size_t)HW_];
            float t3 = p[3 * (size_t)HW_];
            float t4 = p[4 * (size_t)HW_];

            float bxv = sigmoidf_(t0) + cx;
            float byv = sigmoidf_(t1) + cy;
            float bw  = sx * s_anch[2 * a]     * expf(t2);
            float bh  = sy * s_anch[2 * a + 1] * expf(t3);
            float x1 = bxv, y1 = byv, x2 = bxv + bw, y2 = byv + bh;
            float ap = (x2 - x1) * (y2 - y1);
            float ov = sigmoidf_(t4);
            bomax = fmaxf(bomax, ov);

            // best over the 32 GT boxes for this anchor
            float ai = 0.0f, au = 1.0f;
            int   am = 0;
            #pragma unroll 8
            for (int m = 0; m < M_; ++m) {
                float wxi = fminf(x2, s_g[m][2]) - fmaxf(x1, s_g[m][0]);
                float hyi = fminf(y2, s_g[m][3]) - fmaxf(y1, s_g[m][1]);
                wxi = fmaxf(wxi, 0.0f);
                hyi = fmaxf(hyi, 0.0f);
                float inter = wxi * hyi;
                float uni = ap + s_area[m] - inter;
                if (inter * au > ai * uni) { ai = inter; au = uni; am = m; }
            }
            // compare against best anchor so far
            bool upd = (a == 0) || (ai * best_u > best_i * au);
            if (upd) {
                best_i = ai; best_u = au; best_a = a; best_m = am;
                sxl = x1; syl = y1; sxr = x2; syr = y2; so = ov;
            }
        }

        const bool selc = best_i > 0.0f;
        const float miou = best_i / best_u;

        if (selc) {
            float d = so - miou;
            obj_s = d * d;

            const float* g = s_g[best_m];
            float d0 = sxl - g[0];
            float d1 = syl - g[1];
            float d2 = sqrtf(sxr) - sqrtf(g[2]);
            float d3 = sqrtf(syr) - sqrtf(g[3]);
            bbox_s = d0 * d0 + d1 * d1 + d2 * d2 + d3 * d3;

            // classification CE on best anchor's 20 scores
            const float* ps = x + nbase + (size_t)(best_a * 25 + 5) * HW_;
            float sc[C_];
            float mx = -1e30f;
            #pragma unroll
            for (int j = 0; j < C_; ++j) {
                sc[j] = ps[(size_t)j * HW_];
                mx = fmaxf(mx, sc[j]);
            }
            float se = 0.0f;
            #pragma unroll
            for (int j = 0; j < C_; ++j) se += __expf(sc[j] - mx);
            const int lab = s_lab[best_m];
            float scl = sc[0];
            #pragma unroll
            for (int j = 1; j < C_; ++j) scl = (j == lab) ? sc[j] : scl;
            clf_s = mx + __logf(se) - scl;
        } else {
            obj_s = 0.5f * bomax * bomax;
        }
    }

    // ---- wave(64) reduce, then one atomic per wave ----
    #pragma unroll
    for (int off = 32; off > 0; off >>= 1) {
        obj_s  += __shfl_down(obj_s,  off, 64);
        bbox_s += __shfl_down(bbox_s, off, 64);
        clf_s  += __shfl_down(clf_s,  off, 64);
    }
    if ((tid & 63) == 0) {
        atomicAdd(&out[0], obj_s);
        atomicAdd(&out[1], bbox_s);
        atomicAdd(&out[2], clf_s);
    }
}

extern "C" void kernel_launch(void* const* d_in, const int* in_sizes, int n_in,
                              void* d_out, int out_size, void* d_ws, size_t ws_size,
                              hipStream_t stream) {
    const float* x    = (const float*)d_in[0];
    const float* anch = (const float*)d_in[1];
    const float* gt   = (const float*)d_in[2];
    const int*   gl   = (const int*)d_in[3];
    const void*  ih   = d_in[4];
    const void*  iw   = d_in[5];
    float* out = (float*)d_out;

    hipMemsetAsync(out, 0, 3 * sizeof(float), stream);

    dim3 grid((HW_ + 255) / 256, N_);
    yolo_loss_kernel<<<grid, dim3(256), 0, stream>>>(x, anch, gt, gl, ih, iw, out);
}

// Round 2
// 145.017 us; speedup vs baseline: 1.5828x; 1.5828x over previous
//
#include <hip/hip_runtime.h>
#include <math.h>

#define A_ 5
#define C_ 20
#define N_ 64
#define H_ 52
#define W_ 52
#define HW_ (H_ * W_)       // 2704
#define M_ 32
#define CH_ (A_ * (5 + C_)) // 125
#define NBLK_X 11           // ceil(2704/256)
#define NBLK (NBLK_X * N_)  // 704

__device__ __forceinline__ float sigmoidf_(float v) {
    return 1.0f / (1.0f + __expf(-v));
}

__global__ __launch_bounds__(256) void yolo_main_kernel(
    const float* __restrict__ x,       // (N, 125, H, W)
    const float* __restrict__ anchors, // (5, 2)
    const float* __restrict__ gt,      // (N, 32, 4)
    const int* __restrict__ glab,      // (N, 32)
    const void* img_h_p, const void* img_w_p,
    float* __restrict__ ws)            // (NBLK, 3) partial sums
{
    __shared__ float s_g[M_][4];
    __shared__ float s_area[M_];
    __shared__ int   s_lab[M_];
    __shared__ float s_anch[A_ * 2];
    __shared__ float s_red[4][3];

    const int n = blockIdx.y;
    const int tid = threadIdx.x;
    const int cell = blockIdx.x * 256 + tid;

    // ---- stage GT boxes / areas / labels / anchors into LDS ----
    if (tid < M_) {
        float g0 = gt[((size_t)n * M_ + tid) * 4 + 0];
        float g1 = gt[((size_t)n * M_ + tid) * 4 + 1];
        float g2 = gt[((size_t)n * M_ + tid) * 4 + 2];
        float g3 = gt[((size_t)n * M_ + tid) * 4 + 3];
        s_g[tid][0] = g0; s_g[tid][1] = g1;
        s_g[tid][2] = g2; s_g[tid][3] = g3;
        s_area[tid] = (g2 - g0) * (g3 - g1);
        s_lab[tid] = glab[n * M_ + tid];
    } else if (tid >= 64 && tid < 64 + A_ * 2) {
        s_anch[tid - 64] = anchors[tid - 64];
    }
    __syncthreads();

    // ---- decode img scale (int per spec; float-bit-pattern fallback) ----
    int ibw = *(const int*)img_w_p;
    float img_w = (ibw > 0 && ibw < 1000000) ? (float)ibw : *(const float*)img_w_p;
    int ibh = *(const int*)img_h_p;
    float img_h = (ibh > 0 && ibh < 1000000) ? (float)ibh : *(const float*)img_h_p;
    const float sx = img_w / (float)W_;   // 32
    const float sy = img_h / (float)H_;   // 32

    float obj_s = 0.0f, bbox_s = 0.0f, clf_s = 0.0f;

    if (cell < HW_) {
        const int wi = cell % W_;
        const int hi = cell / W_;
        const float cx = (float)wi * sx;
        const float cy = (float)hi * sy;

        // running best over anchors (cross-mult iou comparison, first-max ties)
        float best_i = 0.0f, best_u = 1.0f;
        int   best_a = 0, best_m = 0;
        float sxl = 0.f, syl = 0.f, sxr = 0.f, syr = 0.f, so = 0.f;
        float bomax = -1e30f;

        const size_t nbase = (size_t)n * CH_ * HW_ + (size_t)cell;

        #pragma unroll
        for (int a = 0; a < A_; ++a) {
            const float* p = x + nbase + (size_t)a * 25 * HW_;
            float t0 = p[0];
            float t1 = p[HW_];
            float t2 = p[2 * (size_t)HW_];
            float t3 = p[3 * (size_t)HW_];
            float t4 = p[4 * (size_t)HW_];

            float bxv = sigmoidf_(t0) + cx;
            float byv = sigmoidf_(t1) + cy;
            float bw  = sx * s_anch[2 * a]     * __expf(t2);
            float bh  = sy * s_anch[2 * a + 1] * __expf(t3);
            float x1 = bxv, y1 = byv, x2 = bxv + bw, y2 = byv + bh;
            float ap = (x2 - x1) * (y2 - y1);
            float ov = sigmoidf_(t4);
            bomax = fmaxf(bomax, ov);

            // best over the 32 GT boxes for this anchor
            float ai = 0.0f, au = 1.0f;
            int   am = 0;
            #pragma unroll 8
            for (int m = 0; m < M_; ++m) {
                float wxi = fminf(x2, s_g[m][2]) - fmaxf(x1, s_g[m][0]);
                float hyi = fminf(y2, s_g[m][3]) - fmaxf(y1, s_g[m][1]);
                wxi = fmaxf(wxi, 0.0f);
                hyi = fmaxf(hyi, 0.0f);
                float inter = wxi * hyi;
                float uni = ap + s_area[m] - inter;
                if (inter * au > ai * uni) { ai = inter; au = uni; am = m; }
            }
            // compare against best anchor so far
            bool upd = (a == 0) || (ai * best_u > best_i * au);
            if (upd) {
                best_i = ai; best_u = au; best_a = a; best_m = am;
                sxl = x1; syl = y1; sxr = x2; syr = y2; so = ov;
            }
        }

        const bool selc = best_i > 0.0f;
        const float miou = best_i / best_u;

        if (selc) {
            float d = so - miou;
            obj_s = d * d;

            const float* g = s_g[best_m];
            float d0 = sxl - g[0];
            float d1 = syl - g[1];
            float d2 = sqrtf(sxr) - sqrtf(g[2]);
            float d3 = sqrtf(syr) - sqrtf(g[3]);
            bbox_s = d0 * d0 + d1 * d1 + d2 * d2 + d3 * d3;

            // classification CE on best anchor's 20 scores
            const float* ps = x + nbase + (size_t)(best_a * 25 + 5) * HW_;
            float sc[C_];
            float mx = -1e30f;
            #pragma unroll
            for (int j = 0; j < C_; ++j) {
                sc[j] = ps[(size_t)j * HW_];
                mx = fmaxf(mx, sc[j]);
            }
            float se = 0.0f;
            #pragma unroll
            for (int j = 0; j < C_; ++j) se += __expf(sc[j] - mx);
            const int lab = s_lab[best_m];
            float scl = sc[0];
            #pragma unroll
            for (int j = 1; j < C_; ++j) scl = (j == lab) ? sc[j] : scl;
            clf_s = mx + __logf(se) - scl;
        } else {
            obj_s = 0.5f * bomax * bomax;
        }
    }

    // ---- wave(64) reduce ----
    #pragma unroll
    for (int off = 32; off > 0; off >>= 1) {
        obj_s  += __shfl_down(obj_s,  off, 64);
        bbox_s += __shfl_down(bbox_s, off, 64);
        clf_s  += __shfl_down(clf_s,  off, 64);
    }
    const int wid = tid >> 6;
    if ((tid & 63) == 0) {
        s_red[wid][0] = obj_s;
        s_red[wid][1] = bbox_s;
        s_red[wid][2] = clf_s;
    }
    __syncthreads();
    // ---- block reduce → contention-free partial store (no atomics) ----
    if (tid == 0) {
        float o = 0.f, b = 0.f, c = 0.f;
        #pragma unroll
        for (int w = 0; w < 4; ++w) {
            o += s_red[w][0]; b += s_red[w][1]; c += s_red[w][2];
        }
        const int bid = blockIdx.y * gridDim.x + blockIdx.x;
        ws[bid * 3 + 0] = o;
        ws[bid * 3 + 1] = b;
        ws[bid * 3 + 2] = c;
    }
}

__global__ __launch_bounds__(256) void yolo_reduce_kernel(
    const float* __restrict__ ws, float* __restrict__ out)
{
    __shared__ float s_red[4][3];
    const int tid = threadIdx.x;
    float o = 0.f, b = 0.f, c = 0.f;
    for (int e = tid; e < NBLK; e += 256) {
        o += ws[e * 3 + 0];
        b += ws[e * 3 + 1];
        c += ws[e * 3 + 2];
    }
    #pragma unroll
    for (int off = 32; off > 0; off >>= 1) {
        o += __shfl_down(o, off, 64);
        b += __shfl_down(b, off, 64);
        c += __shfl_down(c, off, 64);
    }
    const int wid = tid >> 6;
    if ((tid & 63) == 0) {
        s_red[wid][0] = o; s_red[wid][1] = b; s_red[wid][2] = c;
    }
    __syncthreads();
    if (tid == 0) {
        float oo = 0.f, bb = 0.f, cc = 0.f;
        #pragma unroll
        for (int w = 0; w < 4; ++w) {
            oo += s_red[w][0]; bb += s_red[w][1]; cc += s_red[w][2];
        }
        out[0] = oo; out[1] = bb; out[2] = cc;
    }
}

extern "C" void kernel_launch(void* const* d_in, const int* in_sizes, int n_in,
                              void* d_out, int out_size, void* d_ws, size_t ws_size,
                              hipStream_t stream) {
    const float* x    = (const float*)d_in[0];
    const float* anch = (const float*)d_in[1];
    const float* gt   = (const float*)d_in[2];
    const int*   gl   = (const int*)d_in[3];
    const void*  ih   = d_in[4];
    const void*  iw   = d_in[5];
    float* out = (float*)d_out;
    float* ws  = (float*)d_ws;

    dim3 grid(NBLK_X, N_);
    yolo_main_kernel<<<grid, dim3(256), 0, stream>>>(x, anch, gt, gl, ih, iw, ws);
    yolo_reduce_kernel<<<1, 256, 0, stream>>>(ws, out);
}

// Round 3
// 142.582 us; speedup vs baseline: 1.6098x; 1.0171x over previous
//
#include <hip/hip_runtime.h>
#include <math.h>

#define A_ 5
#define C_ 20
#define N_ 64
#define H_ 52
#define W_ 52
#define HW_ (H_ * W_)        // 2704
#define M_ 32
#define CH_ (A_ * (5 + C_))  // 125
#define CPB 64               // cells per block
#define NBLK_X ((HW_ + CPB - 1) / CPB)  // 43
#define NBLK (NBLK_X * N_)              // 2752

// Block = 320 threads = 5 waves; wave a computes anchor a for 64 cells.
// GT boxes are wave-uniform loads (s_load path); cross-anchor argmax via LDS.
__global__ __launch_bounds__(320) void yolo_main(
    const float* __restrict__ x,       // (N, 125, H, W)
    const float* __restrict__ anchors, // (5, 2)
    const float* __restrict__ gt,      // (N, 32, 4)
    const int* __restrict__ glab,      // (N, 32)
    const void* img_h_p, const void* img_w_p,
    float* __restrict__ ws)            // (NBLK, 3)
{
    // SoA exchange: [component][anchor][cell] — conflict-free (stride 1 in cell)
    __shared__ float s_c[8][A_][CPB];

    const int tid  = threadIdx.x;
    const int a    = tid >> 6;    // anchor 0..4 (wave id)
    const int lane = tid & 63;    // cell within block chunk
    const int n    = blockIdx.y;
    const int cell = blockIdx.x * CPB + lane;
    const bool valid = cell < HW_;

    // img scale (int per spec; float-bit-pattern fallback)
    int ibw = *(const int*)img_w_p;
    float img_w = (ibw > 0 && ibw < 1000000) ? (float)ibw : *(const float*)img_w_p;
    int ibh = *(const int*)img_h_p;
    float img_h = (ibh > 0 && ibh < 1000000) ? (float)ibh : *(const float*)img_h_p;
    const float sx = img_w / (float)W_;   // 32
    const float sy = img_h / (float)H_;   // 32

    const float ax = anchors[2 * a];       // wave-uniform
    const float ay = anchors[2 * a + 1];

    float bi = 0.f, bu = 1.f;   // best inter/union for this anchor (cross-mult argmax)
    int   bm = 0;
    float x1 = 0.f, y1 = 0.f, x2 = 0.f, y2 = 0.f, ov = 0.f;

    if (valid) {
        const int wi = cell % W_;
        const int hi = cell / W_;
        const size_t base = (size_t)n * CH_ * HW_ + (size_t)a * 25 * HW_ + cell;
        float t0 = x[base];
        float t1 = x[base + (size_t)HW_];
        float t2 = x[base + 2 * (size_t)HW_];
        float t3 = x[base + 3 * (size_t)HW_];
        float t4 = x[base + 4 * (size_t)HW_];

        float bx = 1.f / (1.f + __expf(-t0)) + (float)wi * sx;
        float by = 1.f / (1.f + __expf(-t1)) + (float)hi * sy;
        float bw = sx * ax * __expf(t2);
        float bh = sy * ay * __expf(t3);
        x1 = bx; y1 = by; x2 = bx + bw; y2 = by + bh;
        ov = 1.f / (1.f + __expf(-t4));
        // match reference exactly: area from corner differences
        float ap = (x2 - x1) * (y2 - y1);

        const float4* gtv = (const float4*)(gt + (size_t)n * M_ * 4);
        #pragma unroll 8
        for (int m = 0; m < M_; ++m) {
            float4 g = gtv[m];                 // uniform address -> scalar load
            float area = (g.z - g.x) * (g.w - g.y);
            float wxi = fminf(x2, g.z) - fmaxf(x1, g.x);
            float hyi = fminf(y2, g.w) - fmaxf(y1, g.y);
            wxi = fmaxf(wxi, 0.f);
            hyi = fmaxf(hyi, 0.f);
            float inter = wxi * hyi;
            float uni = ap + area - inter;
            if (inter * bu > bi * uni) { bi = inter; bu = uni; bm = m; }
        }
    }

    s_c[0][a][lane] = bi;
    s_c[1][a][lane] = bu;
    s_c[2][a][lane] = x1;
    s_c[3][a][lane] = y1;
    s_c[4][a][lane] = x2;
    s_c[5][a][lane] = y2;
    s_c[6][a][lane] = ov;
    s_c[7][a][lane] = __int_as_float(bm);
    __syncthreads();

    // ---- tail: wave 0 selects best anchor per cell and computes losses ----
    if (tid < 64) {
        float obj = 0.f, bbx = 0.f, clf = 0.f;

        float Bi = 0.f, Bu = 1.f;
        int Ba = 0, Bm = 0;
        float X1 = 0.f, Y1 = 0.f, X2 = 0.f, Y2 = 0.f, O = 0.f;
        float bomax = -1e30f;
        #pragma unroll
        for (int aa = 0; aa < A_; ++aa) {
            float ci = s_c[0][aa][lane];
            float cu = s_c[1][aa][lane];
            float co = s_c[6][aa][lane];
            bomax = fmaxf(bomax, co);
            bool upd = (aa == 0) || (ci * Bu > Bi * cu);
            if (upd) {
                Bi = ci; Bu = cu; Ba = aa;
                Bm = __float_as_int(s_c[7][aa][lane]);
                X1 = s_c[2][aa][lane]; Y1 = s_c[3][aa][lane];
                X2 = s_c[4][aa][lane]; Y2 = s_c[5][aa][lane];
                O = co;
            }
        }

        if (valid) {
            if (Bi > 0.f) {
                float miou = Bi / Bu;
                float d = O - miou;
                obj = d * d;

                float4 g = ((const float4*)gt)[n * M_ + Bm];  // divergent Bm, vector load
                float d0 = X1 - g.x;
                float d1 = Y1 - g.y;
                float d2 = sqrtf(X2) - sqrtf(g.z);
                float d3 = sqrtf(Y2) - sqrtf(g.w);
                bbx = d0 * d0 + d1 * d1 + d2 * d2 + d3 * d3;

                // CE via online softmax (no 20-reg array)
                const size_t sb = (size_t)n * CH_ * HW_ + (size_t)(Ba * 25 + 5) * HW_ + cell;
                const int lab = glab[n * M_ + Bm];
                float mx = -1e30f, se = 0.f, scl = 0.f;
                #pragma unroll
                for (int j = 0; j < C_; ++j) {
                    float v = x[sb + (size_t)j * HW_];
                    float nm = fmaxf(mx, v);
                    se = se * __expf(mx - nm) + __expf(v - nm);
                    mx = nm;
                    scl = (j == lab) ? v : scl;
                }
                clf = mx + __logf(se) - scl;
            } else {
                obj = 0.5f * bomax * bomax;
            }
        }

        #pragma unroll
        for (int off = 32; off > 0; off >>= 1) {
            obj += __shfl_down(obj, off, 64);
            bbx += __shfl_down(bbx, off, 64);
            clf += __shfl_down(clf, off, 64);
        }
        if (tid == 0) {
            const int bid = blockIdx.y * gridDim.x + blockIdx.x;
            ws[bid * 3 + 0] = obj;
            ws[bid * 3 + 1] = bbx;
            ws[bid * 3 + 2] = clf;
        }
    }
}

__global__ __launch_bounds__(256) void yolo_reduce(
    const float* __restrict__ ws, float* __restrict__ out)
{
    __shared__ float s_red[4][3];
    const int tid = threadIdx.x;
    float o = 0.f, b = 0.f, c = 0.f;
    for (int e = tid; e < NBLK; e += 256) {
        o += ws[e * 3 + 0];
        b += ws[e * 3 + 1];
        c += ws[e * 3 + 2];
    }
    #pragma unroll
    for (int off = 32; off > 0; off >>= 1) {
        o += __shfl_down(o, off, 64);
        b += __shfl_down(b, off, 64);
        c += __shfl_down(c, off, 64);
    }
    const int wid = tid >> 6;
    if ((tid & 63) == 0) {
        s_red[wid][0] = o; s_red[wid][1] = b; s_red[wid][2] = c;
    }
    __syncthreads();
    if (tid == 0) {
        float oo = 0.f, bb = 0.f, cc = 0.f;
        #pragma unroll
        for (int w = 0; w < 4; ++w) {
            oo += s_red[w][0]; bb += s_red[w][1]; cc += s_red[w][2];
        }
        out[0] = oo; out[1] = bb; out[2] = cc;
    }
}

extern "C" void kernel_launch(void* const* d_in, const int* in_sizes, int n_in,
                              void* d_out, int out_size, void* d_ws, size_t ws_size,
                              hipStream_t stream) {
    const float* x    = (const float*)d_in[0];
    const float* anch = (const float*)d_in[1];
    const float* gt   = (const float*)d_in[2];
    const int*   gl   = (const int*)d_in[3];
    const void*  ih   = d_in[4];
    const void*  iw   = d_in[5];
    float* out = (float*)d_out;
    float* ws  = (float*)d_ws;

    dim3 grid(NBLK_X, N_);
    yolo_main<<<grid, dim3(320), 0, stream>>>(x, anch, gt, gl, ih, iw, ws);
    yolo_reduce<<<1, 256, 0, stream>>>(ws, out);
}